// Round 4
// baseline (980.615 us; speedup 1.0000x reference)
//
#include <hip/hip_runtime.h>
#include <hip/hip_bf16.h>

#define WIDTH_ 2560
#define LRU_   2560
#define HEADS_ 8
#define BW_    320
#define DCONV_ 4
#define BB     4
#define LL     2048
#define MROWS  (BB*LL)          // 8192
#define NCH    32               // scan chunks
#define CLEN   (LL/NCH)         // 64

typedef unsigned short ushort_t;
typedef __attribute__((ext_vector_type(8))) short short8;
typedef __attribute__((ext_vector_type(4))) float f32x4;

__device__ __forceinline__ unsigned short f2bf(float f) {
  union { float f; unsigned u; } v; v.f = f;
  unsigned r = v.u + 0x7fffu + ((v.u >> 16) & 1u);
  return (unsigned short)(r >> 16);
}
__device__ __forceinline__ float bf2f(unsigned short h) {
  union { unsigned u; float f; } v; v.u = ((unsigned)h) << 16;
  return v.f;
}
__device__ __forceinline__ void async_load16(const void* g, void* l) {
  __builtin_amdgcn_global_load_lds(
      (const __attribute__((address_space(1))) unsigned*)g,
      (__attribute__((address_space(3))) unsigned*)l, 16, 0, 0);
}
__device__ __forceinline__ float sigmoidf_(float x) {
  return 1.f / (1.f + __expf(-x));
}

// ---------------- conversion kernels ----------------
__global__ void cvt_bf16x4(const float4* __restrict__ in, ushort4* __restrict__ out, int n4) {
  int i = blockIdx.x * blockDim.x + threadIdx.x;
  if (i >= n4) return;
  float4 v = in[i];
  ushort4 o;
  o.x = f2bf(v.x); o.y = f2bf(v.y); o.z = f2bf(v.z); o.w = f2bf(v.w);
  out[i] = o;
}

// gwT[h][rowoff + j][i] = w[h][i][j]   (bf16), head stride 640*320
__global__ void cvt_transpose(const float* __restrict__ w, ushort_t* __restrict__ gwT,
                              int rowoff, int n) {
  int i = blockIdx.x * blockDim.x + threadIdx.x;
  if (i >= n) return;
  int ii = i % BW_;
  int j  = (i / BW_) % BW_;
  int h  = i / (BW_ * BW_);
  gwT[((size_t)h * 640 + rowoff + j) * BW_ + ii] = f2bf(w[((size_t)h * BW_ + ii) * BW_ + j]);
}

// ctab[e] = -8 * softplus(a_param[e])
__global__ void ctab_kernel(const float* __restrict__ apar, float* __restrict__ ctab) {
  int e = blockIdx.x * blockDim.x + threadIdx.x;
  if (e >= LRU_) return;
  float ap = apar[e];
  float sp = (ap > 15.f) ? ap : log1pf(expf(ap));
  ctab[e] = -8.f * sp;
}

// ---------------- 256x256 GEMM, 4-buffer K-step pipeline, counted vmcnt ---------
// C[M,N] = A[M,2560](bf16) * B[N,2560](bf16)^T ; grid.x = 32 * (N/256)
// EPI 0: f32 store + bias   EPI 1: split store bf16 (col<2560 -> C0 +bias, else C1)
// LDS: A bufs p*16384 (p=0..3), B bufs 65536 + p*16384; layout [ksub(4)][row(256)][16B]
// Pipeline: stage K-step t+3 after barrier at t (target buf idle since t-1);
// vmcnt(8) at t => buf[t&3] loads (issued t-3) complete; 8 loads stay in flight.
template<int EPI>
__global__ __launch_bounds__(512, 2)
void gemm8p(const ushort_t* __restrict__ A,
            const ushort_t* __restrict__ B,
            void* __restrict__ C0, void* __restrict__ C1,
            const float* __restrict__ bias) {
  constexpr int KK = 2560, NT = KK / 32;   // 80 K-steps of BK=32
  __shared__ char smem[131072];
  const int tid = threadIdx.x;
  const int lane = tid & 63, w = tid >> 6;
  const int wr = w >> 2, wc = w & 3;
  const int l15 = lane & 15, l4 = lane >> 4;

  // XCD-chunked mapping: XCD x owns tm-band [4x,4x+4), tn fastest (bijective)
  const int nblk = gridDim.x;
  const int TN = nblk >> 5;                // nblk / 32
  const int x8 = blockIdx.x & 7, c = blockIdx.x >> 3;
  const int tm = (x8 * 4 + c / TN) * 256;
  const int tn = (c % TN) * 256;

  // staging: lb=(u*512+tid)*16 -> LDS [ksub][m][16B]; global src pre-scattered
  const char* aSrc[2]; const char* bSrc[2]; int ldst[2];
#pragma unroll
  for (int u = 0; u < 2; ++u) {
    int lb = (u * 512 + tid) * 16;
    int ks = lb >> 12, m = (lb >> 4) & 255;
    aSrc[u] = (const char*)A + (size_t)(tm + m) * (KK * 2) + ks * 16;
    bSrc[u] = (const char*)B + (size_t)(tn + m) * (KK * 2) + ks * 16;
    ldst[u] = lb;
  }

  f32x4 acc[8][4] = {};

  // prologue: stage K-steps 0,1,2 into bufs 0,1,2 (12 loads)
#pragma unroll
  for (int kt = 0; kt < 3; ++kt)
#pragma unroll
    for (int u = 0; u < 2; ++u) {
      async_load16(aSrc[u] + kt * 64, smem + kt * 16384 + ldst[u]);
      async_load16(bSrc[u] + kt * 64, smem + 65536 + kt * 16384 + ldst[u]);
    }

  const int aRd = (l4 * 256 + wr * 128 + l15) * 16;
  const int bRd = (l4 * 256 + wc * 64 + l15) * 16 + 65536;

  for (int t = 0; t < NT; ++t) {
    if (t < NT - 2)       asm volatile("s_waitcnt vmcnt(8)" ::: "memory");
    else if (t == NT - 2) asm volatile("s_waitcnt vmcnt(4)" ::: "memory");
    else                  asm volatile("s_waitcnt vmcnt(0)" ::: "memory");
    __builtin_amdgcn_s_barrier();
    if (t + 3 < NT) {
      const int kt = t + 3, p = kt & 3;
#pragma unroll
      for (int u = 0; u < 2; ++u) {
        async_load16(aSrc[u] + kt * 64, smem + p * 16384 + ldst[u]);
        async_load16(bSrc[u] + kt * 64, smem + 65536 + p * 16384 + ldst[u]);
      }
    }
    const char* base = smem + (t & 3) * 16384;
    short8 bfrag[4], afrag[4];
#pragma unroll
    for (int nf = 0; nf < 4; ++nf)
      bfrag[nf] = *(const short8*)(base + bRd + nf * 256);
#pragma unroll
    for (int mf = 0; mf < 4; ++mf)
      afrag[mf] = *(const short8*)(base + aRd + mf * 256);
    __builtin_amdgcn_s_setprio(1);
#pragma unroll
    for (int mf = 0; mf < 4; ++mf)
#pragma unroll
      for (int nf = 0; nf < 4; ++nf)
        acc[mf][nf] = __builtin_amdgcn_mfma_f32_16x16x32_bf16(
            afrag[mf], bfrag[nf], acc[mf][nf], 0, 0, 0);
    __builtin_amdgcn_s_setprio(0);
#pragma unroll
    for (int mf = 0; mf < 4; ++mf)
      afrag[mf] = *(const short8*)(base + aRd + 1024 + mf * 256);
    __builtin_amdgcn_s_setprio(1);
#pragma unroll
    for (int mf = 0; mf < 4; ++mf)
#pragma unroll
      for (int nf = 0; nf < 4; ++nf)
        acc[4 + mf][nf] = __builtin_amdgcn_mfma_f32_16x16x32_bf16(
            afrag[mf], bfrag[nf], acc[4 + mf][nf], 0, 0, 0);
    __builtin_amdgcn_s_setprio(0);
  }

  // epilogue: C row = (lane>>4)*4 + r, col = lane&15
  const int crow0 = tm + wr * 128 + l4 * 4;
  const int ccol0 = tn + wc * 64 + l15;
#pragma unroll
  for (int m = 0; m < 8; ++m)
#pragma unroll
    for (int n = 0; n < 4; ++n) {
      const int col = ccol0 + n * 16;
#pragma unroll
      for (int r = 0; r < 4; ++r) {
        const int row = crow0 + m * 16 + r;
        float v = acc[m][n][r];
        if (EPI == 0) {
          ((float*)C0)[(size_t)row * 2560 + col] = v + bias[col];
        } else {
          if (col < 2560)
            ((ushort_t*)C0)[(size_t)row * 2560 + col] = f2bf(v + bias[col]);
          else
            ((ushort_t*)C1)[(size_t)row * 2560 + (col - 2560)] = f2bf(v);
        }
      }
    }
}

// ---------------- gate GEMM (m97 structure, fused gx+ga epilogue) ----------------
// per head z: C' = xc_head @ gwT_z^T ; gwT_z = [gxw_z^T ; gaw_z^T]  (640 x 320)
__global__ __launch_bounds__(256, 2)
void gate_gemm(const ushort_t* __restrict__ A,      // xcbf [8192][2560]
               const ushort_t* __restrict__ Bw,     // gwT [8][640][320]
               ushort_t* __restrict__ GX,           // T2 [8192][2560]
               ushort_t* __restrict__ AAo,          // AA [8192][2560]
               const float* __restrict__ gxb, const float* __restrict__ gab,
               const float* __restrict__ ctab, const int* __restrict__ seg) {
  constexpr int BM = 128, BN = 64, BK = 32, WTN = 32, NF = 2;
  __shared__ ushort_t lds_a[BM * BK];
  __shared__ ushort_t lds_b[BN * BK];

  const int tid = threadIdx.x;
  const int w = tid >> 6, lane = tid & 63;
  const int wr = w >> 1, wc = w & 1;
  const int tm = blockIdx.x * BM;
  const int tn = blockIdx.y * BN;     // 0..576, region: <320 GX, >=320 AA
  const int z = blockIdx.z;
  const ushort_t* Ab = A + (size_t)z * BW_;
  const ushort_t* Bb = Bw + (size_t)z * 640 * BW_ + (size_t)tn * BW_;

  f32x4 acc[4][NF] = {};
  const int ksub = (lane >> 4) * 8;
  const int rA = wr * 64 + (lane & 15);
  const int rB = wc * WTN + (lane & 15);

  for (int k0 = 0; k0 < BW_; k0 += BK) {
#pragma unroll
    for (int i = 0; i < 2; ++i) {
      int bo = (i * 256 + tid) * 16;
      int row = bo >> 6, colb = bo & 63;
      async_load16((const char*)Ab + (size_t)(tm + row) * LRU_ * 2 + (size_t)k0 * 2 + colb,
                   (char*)lds_a + bo);
    }
    {
      int bo = tid * 16;
      int row = bo >> 6, colb = bo & 63;
      async_load16((const char*)Bb + (size_t)row * BW_ * 2 + (size_t)k0 * 2 + colb,
                   (char*)lds_b + bo);
    }
    __syncthreads();
    short8 af[4], bfr[NF];
#pragma unroll
    for (int mf = 0; mf < 4; ++mf)
      af[mf] = *(const short8*)&lds_a[(rA + mf * 16) * BK + ksub];
#pragma unroll
    for (int nf = 0; nf < NF; ++nf)
      bfr[nf] = *(const short8*)&lds_b[(rB + nf * 16) * BK + ksub];
#pragma unroll
    for (int mf = 0; mf < 4; ++mf)
#pragma unroll
      for (int nf = 0; nf < NF; ++nf)
        acc[mf][nf] = __builtin_amdgcn_mfma_f32_16x16x32_bf16(af[mf], bfr[nf], acc[mf][nf], 0, 0, 0);
    __syncthreads();
  }

  const int crow0 = tm + wr * 64 + ((lane >> 4) << 2);
  const int ccol0 = tn + wc * WTN + (lane & 15);
#pragma unroll
  for (int mf = 0; mf < 4; ++mf) {
#pragma unroll
    for (int nf = 0; nf < NF; ++nf) {
      const int cih = ccol0 + nf * 16;     // 0..639 within head
#pragma unroll
      for (int r = 0; r < 4; ++r) {
        const int row = crow0 + mf * 16 + r;
        if (cih < BW_) {
          const int gc = z * BW_ + cih;
          float v = acc[mf][nf][r] + gxb[gc];
          float xc = bf2f(A[(size_t)row * LRU_ + gc]);
          GX[(size_t)row * LRU_ + gc] = f2bf(xc * sigmoidf_(v));
        } else {
          const int gc = z * BW_ + cih - BW_;
          float v = acc[mf][nf][r] + gab[gc];
          float la = ctab[gc] * sigmoidf_(v);
          float av = (seg[row] == 0) ? 0.f : expf(la);
          AAo[(size_t)row * LRU_ + gc] = f2bf(av);
        }
      }
    }
  }
}

// ---------------- conv (causal depthwise, window 4), bf16, x8 vectorized ----------
__global__ void conv_kernel(const ushort_t* __restrict__ xl, const float* __restrict__ convw,
                            const float* __restrict__ convb, ushort_t* __restrict__ xcbf) {
  int i = blockIdx.x * blockDim.x + threadIdx.x;     // over MROWS*LRU/8
  if (i >= MROWS * LRU_ / 8) return;
  int e0 = (i % (LRU_ / 8)) * 8;
  int t = (i / (LRU_ / 8)) % LL;
  int b = i / ((LRU_ / 8) * LL);
  size_t rowb = ((size_t)b * LL + t) * LRU_;
  const ushort_t* base = xl + rowb + e0;
  short8 v0 = {}, v1 = {}, v2 = {}, v3;
  if (t >= 3) v0 = *(const short8*)(base - 3 * LRU_);
  if (t >= 2) v1 = *(const short8*)(base - 2 * LRU_);
  if (t >= 1) v2 = *(const short8*)(base - 1 * LRU_);
  v3 = *(const short8*)(base);
  ushort_t o[8];
#pragma unroll
  for (int u = 0; u < 8; ++u) {
    float4 wv = ((const float4*)convw)[e0 + u];
    float acc = convb[e0 + u];
    acc += wv.x * bf2f((ushort_t)v0[u]);
    acc += wv.y * bf2f((ushort_t)v1[u]);
    acc += wv.z * bf2f((ushort_t)v2[u]);
    acc += wv.w * bf2f((ushort_t)v3[u]);
    o[u] = f2bf(acc);
  }
  *(short8*)(xcbf + rowb + e0) = *(short8*)o;
}

__global__ void conv_state_kernel(const ushort_t* __restrict__ xl, const int* __restrict__ cidx,
                                  float* __restrict__ cs) {
  int i = blockIdx.x * blockDim.x + threadIdx.x;
  if (i >= BB * LRU_ * DCONV_) return;
  int e = (i / DCONV_) % LRU_;
  int b = i / (DCONV_ * LRU_);
  int idx = cidx[i];
  int ts = idx - (DCONV_ - 1);
  float v = 0.f;
  if (ts >= 0 && ts < LL) v = bf2f(xl[((size_t)b * LL + ts) * LRU_ + e]);
  cs[i] = v;
}

// ---------------- chunked scan ----------------
__global__ void scanA(const ushort_t* __restrict__ AA, const ushort_t* __restrict__ GX,
                      float* __restrict__ cA, float* __restrict__ cH) {
  int i = blockIdx.x * blockDim.x + threadIdx.x;
  if (i >= BB * NCH * LRU_) return;
  int e = i % LRU_;
  int c = (i / LRU_) % NCH;
  int b = i / (LRU_ * NCH);
  float Ap = 1.f, h = 0.f;
  size_t base = ((size_t)b * LL + (size_t)c * CLEN) * LRU_ + e;
  for (int t = 0; t < CLEN; ++t) {
    size_t j = base + (size_t)t * LRU_;
    float a = bf2f(AA[j]);
    float nx = bf2f(GX[j]) * sqrtf(fmaxf(0.f, 1.f - a * a));
    Ap *= a;
    h = a * h + nx;
  }
  cA[i] = Ap; cH[i] = h;
}

__global__ void scanB(const float* __restrict__ cA, const float* __restrict__ cH,
                      float* __restrict__ hInit) {
  int i = blockIdx.x * blockDim.x + threadIdx.x;
  if (i >= BB * LRU_) return;
  int e = i % LRU_;
  int b = i / LRU_;
  float h = 0.f;
  for (int c = 0; c < NCH; ++c) {
    size_t j = ((size_t)b * NCH + c) * LRU_ + e;
    hInit[j] = h;
    h = cA[j] * h + cH[j];
  }
}

__global__ void scanC(const ushort_t* __restrict__ AA, const ushort_t* __restrict__ GXpre,
                      const float* __restrict__ hInit, const ushort_t* __restrict__ ybf,
                      const float* __restrict__ ybias, float* __restrict__ lastH) {
  int i = blockIdx.x * blockDim.x + threadIdx.x;
  if (i >= BB * NCH * LRU_) return;
  int e = i % LRU_;
  int c = (i / LRU_) % NCH;
  int b = i / (LRU_ * NCH);
  float h = hInit[i];
  float yb = ybias[e];
  ushort_t* pre = (ushort_t*)GXpre;
  size_t base = ((size_t)b * LL + (size_t)c * CLEN) * LRU_ + e;
  for (int t = 0; t < CLEN; ++t) {
    size_t j = base + (size_t)t * LRU_;
    float a = bf2f(AA[j]);
    float nx = bf2f(GXpre[j]) * sqrtf(fmaxf(0.f, 1.f - a * a));
    h = a * h + nx;
    float yv = bf2f(ybf[j]) + yb;
    float g = 0.5f * yv * (1.f + erff(yv * 0.70710678118f));
    pre[j] = f2bf(h * g);
  }
  if (c == NCH - 1) lastH[(size_t)b * LRU_ + e] = h;
}

// ---------------- launch ----------------
extern "C" void kernel_launch(void* const* d_in, const int* in_sizes, int n_in,
                              void* d_out, int out_size, void* d_ws, size_t ws_size,
                              hipStream_t stream) {
  const float* x     = (const float*)d_in[0];
  const int*   seg   = (const int*)d_in[1];
  const int*   cidx  = (const int*)d_in[2];
  const float* Wx    = (const float*)d_in[3];
  const float* bx    = (const float*)d_in[4];
  const float* Wy    = (const float*)d_in[5];
  const float* convw = (const float*)d_in[6];
  const float* convb = (const float*)d_in[7];
  const float* gxw   = (const float*)d_in[8];
  const float* gxb   = (const float*)d_in[9];
  const float* gaw   = (const float*)d_in[10];
  const float* gab   = (const float*)d_in[11];
  const float* apar  = (const float*)d_in[12];
  const float* ybias = (const float*)d_in[13];
  const float* Wout  = (const float*)d_in[14];
  const float* bout  = (const float*)d_in[15];

  float* out    = (float*)d_out;
  float* cs_out = out + (size_t)MROWS * WIDTH_;
  float* lh_out = cs_out + (size_t)BB * LRU_ * DCONV_;

  // scratch inside d_out (dead until the final GEMM rewrites the out region)
  ushort_t* ybf = (ushort_t*)d_out;                               // 41.94 MB
  ushort_t* AA  = (ushort_t*)((char*)d_out + (size_t)41943040);   // 41.94 MB

  const size_t SZ_BIG = (size_t)MROWS * LRU_ * 2;       // 41,943,040
  const size_t SZ_WC  = (size_t)(2 * LRU_) * WIDTH_ * 2;// 26,214,400
  const size_t SZ_GW  = (size_t)HEADS_ * 640 * BW_ * 2; // 3,276,800
  const size_t SZ_SM  = (size_t)BB * NCH * LRU_ * 4;    // 1,310,720
  size_t need = SZ_BIG * 3 + SZ_WC + SZ_GW + 10240 + SZ_SM * 3;
  if (ws_size < need) return;

  char* p = (char*)d_ws;
  ushort_t* xbf   = (ushort_t*)p; p += SZ_BIG;
  ushort_t* wcat  = (ushort_t*)p; p += SZ_WC;   // [Wx ; Wy] bf16, later Wout in first half
  ushort_t* T2    = (ushort_t*)p; p += SZ_BIG;  // xl -> GX -> pre
  ushort_t* xcbf  = (ushort_t*)p; p += SZ_BIG;
  ushort_t* gwT   = (ushort_t*)p; p += SZ_GW;   // [8][640][320] = [gxw^T ; gaw^T]
  float*    ctab  = (float*)p;    p += 10240;
  float*    cA    = (float*)p;    p += SZ_SM;
  float*    cH    = (float*)p;    p += SZ_SM;
  float*    hInit = (float*)p;    p += SZ_SM;
  ushort_t* woutbf = wcat;

  const int BLK = 256;
  cvt_bf16x4<<<(MROWS * WIDTH_ / 4 + BLK - 1) / BLK, BLK, 0, stream>>>(
      (const float4*)x, (ushort4*)xbf, MROWS * WIDTH_ / 4);
  cvt_bf16x4<<<(LRU_ * WIDTH_ / 4 + BLK - 1) / BLK, BLK, 0, stream>>>(
      (const float4*)Wx, (ushort4*)wcat, LRU_ * WIDTH_ / 4);
  cvt_bf16x4<<<(LRU_ * WIDTH_ / 4 + BLK - 1) / BLK, BLK, 0, stream>>>(
      (const float4*)Wy, (ushort4*)(wcat + (size_t)LRU_ * WIDTH_), LRU_ * WIDTH_ / 4);

  // fused: [xl | y] = x @ [Wx;Wy]^T   (N=5120, 640 blocks)
  gemm8p<1><<<640, 512, 0, stream>>>(xbf, wcat, T2, ybf, bx);

  // Wout -> first half of wcat (dead after fused GEMM; stream-ordered)
  cvt_bf16x4<<<(WIDTH_ * LRU_ / 4 + BLK - 1) / BLK, BLK, 0, stream>>>(
      (const float4*)Wout, (ushort4*)woutbf, WIDTH_ * LRU_ / 4);

  conv_kernel<<<(MROWS * LRU_ / 8 + BLK - 1) / BLK, BLK, 0, stream>>>(T2, convw, convb, xcbf);
  conv_state_kernel<<<(BB * LRU_ * DCONV_ + BLK - 1) / BLK, BLK, 0, stream>>>(T2, cidx, cs_out);

  cvt_transpose<<<(HEADS_ * BW_ * BW_ + BLK - 1) / BLK, BLK, 0, stream>>>(gxw, gwT, 0, HEADS_ * BW_ * BW_);
  cvt_transpose<<<(HEADS_ * BW_ * BW_ + BLK - 1) / BLK, BLK, 0, stream>>>(gaw, gwT, BW_, HEADS_ * BW_ * BW_);
  ctab_kernel<<<(LRU_ + BLK - 1) / BLK, BLK, 0, stream>>>(apar, ctab);

  // fused gate GEMM: GX -> T2 (over dead xl), AA -> d_out scratch
  gate_gemm<<<dim3(MROWS / 128, 10, HEADS_), BLK, 0, stream>>>(
      xcbf, gwT, T2, AA, gxb, gab, ctab, seg);

  scanA<<<(BB * NCH * LRU_ + BLK - 1) / BLK, BLK, 0, stream>>>(AA, T2, cA, cH);
  scanB<<<(BB * LRU_ + BLK - 1) / BLK, BLK, 0, stream>>>(cA, cH, hInit);
  scanC<<<(BB * NCH * LRU_ + BLK - 1) / BLK, BLK, 0, stream>>>(AA, T2, hInit, ybf, ybias, lh_out);

  // out = pre @ Wout^T + bout  (N=2560, 320 blocks)
  gemm8p<0><<<320, 512, 0, stream>>>(T2, woutbf, out, nullptr, bout);
}

// Round 5
// 591.768 us; speedup vs baseline: 1.6571x; 1.6571x over previous
//
#include <hip/hip_runtime.h>
#include <hip/hip_bf16.h>

#define WIDTH_ 2560
#define LRU_   2560
#define HEADS_ 8
#define BW_    320
#define DCONV_ 4
#define BB     4
#define LL     2048
#define MROWS  (BB*LL)          // 8192
#define NCH    32               // scan chunks
#define CLEN   (LL/NCH)         // 64

typedef unsigned short ushort_t;
typedef __attribute__((ext_vector_type(8))) short short8;
typedef __attribute__((ext_vector_type(4))) float f32x4;

__device__ __forceinline__ unsigned short f2bf(float f) {
  union { float f; unsigned u; } v; v.f = f;
  unsigned r = v.u + 0x7fffu + ((v.u >> 16) & 1u);
  return (unsigned short)(r >> 16);
}
__device__ __forceinline__ float bf2f(unsigned short h) {
  union { unsigned u; float f; } v; v.u = ((unsigned)h) << 16;
  return v.f;
}
__device__ __forceinline__ void async_load16(const void* g, void* l) {
  __builtin_amdgcn_global_load_lds(
      (const __attribute__((address_space(1))) unsigned*)g,
      (__attribute__((address_space(3))) unsigned*)l, 16, 0, 0);
}
__device__ __forceinline__ float sigmoidf_(float x) {
  return 1.f / (1.f + __expf(-x));
}
// packed [C/8][PL][8] address (ushort units)
__device__ __forceinline__ size_t pkaddr(int e, int m, int PL) {
  return ((size_t)(e >> 3) * PL + m) * 8 + (e & 7);
}

// ------------- transpose-pack: f32 [R][C] -> bf16 packed [C/8][PL][8] @ row RO -----
__global__ void tp_pack(const float* __restrict__ src, ushort_t* __restrict__ dst,
                        int R, int C, int PL, int RO) {
  __shared__ float tile[64][65];
  const int r0 = blockIdx.x * 64, c0 = blockIdx.y * 64;
  const int t = threadIdx.x;
#pragma unroll
  for (int it = 0; it < 4; ++it) {
    int row = it * 16 + (t >> 4);
    int col = (t & 15) * 4;
    *(float4*)&tile[row][col] = *(const float4*)&src[(size_t)(r0 + row) * C + c0 + col];
  }
  __syncthreads();
#pragma unroll
  for (int it = 0; it < 2; ++it) {
    int c8 = it * 4 + (t >> 6);     // 0..7
    int m  = t & 63;
    ushort_t o[8];
#pragma unroll
    for (int j = 0; j < 8; ++j) o[j] = f2bf(tile[m][c8 * 8 + j]);
    *(short8*)&dst[((size_t)(c0 / 8 + c8) * PL + RO + r0 + m) * 8] = *(short8*)o;
  }
}

// gate weights: dst[h*40 + k>>3][RO + n][k&7] = w[h][k][n]   (plane rows = 640)
__global__ void gw_pack(const float* __restrict__ w, ushort_t* __restrict__ dst,
                        int RO, int n_) {
  int i = blockIdx.x * blockDim.x + threadIdx.x;
  if (i >= n_) return;
  int n = i % BW_;
  int k = (i / BW_) % BW_;
  int h = i / (BW_ * BW_);
  dst[((size_t)(h * 40 + (k >> 3)) * 640 + RO + n) * 8 + (k & 7)] =
      f2bf(w[((size_t)h * BW_ + k) * BW_ + n]);
}

// ctab[e] = -8 * softplus(a_param[e])
__global__ void ctab_kernel(const float* __restrict__ apar, float* __restrict__ ctab) {
  int e = blockIdx.x * blockDim.x + threadIdx.x;
  if (e >= LRU_) return;
  float ap = apar[e];
  float sp = (ap > 15.f) ? ap : log1pf(expf(ap));
  ctab[e] = -8.f * sp;
}

// ---------------- 256x256 GEMM on packed operands, 4-buffer counted-vmcnt --------
// A packed [320][8192][8]; B packed [320][NPL][8]; K=2560, BK=32, NT=80
// LDS buf p: A at p*16384, B at 65536+p*16384; layout [slot4][m256][16B]
// EPI 0: f32 row-major store + bias   EPI 1: split packed bf16 (col<2560->C0+bias, else C1)
template<int EPI>
__global__ __launch_bounds__(512, 2)
void gemm_pk(const ushort_t* __restrict__ A,
             const ushort_t* __restrict__ B, int NPL,
             void* __restrict__ C0, void* __restrict__ C1,
             const float* __restrict__ bias) {
  constexpr int NT = 80;
  __shared__ char smem[131072];
  const int tid = threadIdx.x;
  const int lane = tid & 63, w = tid >> 6;
  const int wr = w >> 2, wc = w & 3;
  const int l15 = lane & 15, l4 = lane >> 4;

  // XCD-chunked mapping: XCD x owns tm-band [4x,4x+4), tn fastest (bijective)
  const int nblk = gridDim.x;
  const int TN = nblk >> 5;
  const int x8 = blockIdx.x & 7, c = blockIdx.x >> 3;
  const int tm = (x8 * 4 + c / TN) * 256;
  const int tn = (c % TN) * 256;

  // staging: lb=(u*512+tid)*16 -> slot=lb>>12, m=(lb>>4)&255 ; src contiguous 4KB runs
  const char* aS[2]; const char* bS[2]; int ld[2];
#pragma unroll
  for (int u = 0; u < 2; ++u) {
    int lb = (u * 512 + tid) * 16;
    int slot = lb >> 12, m = (lb >> 4) & 255;
    aS[u] = (const char*)A + ((size_t)slot * MROWS + tm + m) * 16;
    bS[u] = (const char*)B + ((size_t)slot * NPL + tn + m) * 16;
    ld[u] = lb;
  }
  const size_t aStep = (size_t)4 * MROWS * 16;
  const size_t bStep = (size_t)4 * NPL * 16;

  f32x4 acc[8][4] = {};

  // prologue: stage K-steps 0,1,2 into bufs 0,1,2
#pragma unroll
  for (int kt = 0; kt < 3; ++kt)
#pragma unroll
    for (int u = 0; u < 2; ++u) {
      async_load16(aS[u] + kt * aStep, smem + kt * 16384 + ld[u]);
      async_load16(bS[u] + kt * bStep, smem + 65536 + kt * 16384 + ld[u]);
    }

  const int aRd = l4 * 4096 + (wr * 128 + l15) * 16;
  const int bRd = 65536 + l4 * 4096 + (wc * 64 + l15) * 16;

  for (int t = 0; t < NT; ++t) {
    if (t < NT - 2)       asm volatile("s_waitcnt vmcnt(8)" ::: "memory");
    else if (t == NT - 2) asm volatile("s_waitcnt vmcnt(4)" ::: "memory");
    else                  asm volatile("s_waitcnt vmcnt(0)" ::: "memory");
    __builtin_amdgcn_s_barrier();
    if (t + 3 < NT) {
      const int kt = t + 3, p = kt & 3;
#pragma unroll
      for (int u = 0; u < 2; ++u) {
        async_load16(aS[u] + kt * aStep, smem + p * 16384 + ld[u]);
        async_load16(bS[u] + kt * bStep, smem + 65536 + p * 16384 + ld[u]);
      }
    }
    const char* base = smem + (t & 3) * 16384;
    short8 bfrag[4], afrag[4];
#pragma unroll
    for (int nf = 0; nf < 4; ++nf)
      bfrag[nf] = *(const short8*)(base + bRd + nf * 256);
#pragma unroll
    for (int mf = 0; mf < 4; ++mf)
      afrag[mf] = *(const short8*)(base + aRd + mf * 256);
    __builtin_amdgcn_s_setprio(1);
#pragma unroll
    for (int mf = 0; mf < 4; ++mf)
#pragma unroll
      for (int nf = 0; nf < 4; ++nf)
        acc[mf][nf] = __builtin_amdgcn_mfma_f32_16x16x32_bf16(
            afrag[mf], bfrag[nf], acc[mf][nf], 0, 0, 0);
    __builtin_amdgcn_s_setprio(0);
#pragma unroll
    for (int mf = 0; mf < 4; ++mf)
      afrag[mf] = *(const short8*)(base + aRd + 1024 + mf * 256);
    __builtin_amdgcn_s_setprio(1);
#pragma unroll
    for (int mf = 0; mf < 4; ++mf)
#pragma unroll
      for (int nf = 0; nf < 4; ++nf)
        acc[4 + mf][nf] = __builtin_amdgcn_mfma_f32_16x16x32_bf16(
            afrag[mf], bfrag[nf], acc[4 + mf][nf], 0, 0, 0);
    __builtin_amdgcn_s_setprio(0);
  }

  // epilogue: C row = (lane>>4)*4 + r, col = lane&15
  const int crow0 = tm + wr * 128 + l4 * 4;
  const int ccol0 = tn + wc * 64 + l15;
#pragma unroll
  for (int m = 0; m < 8; ++m)
#pragma unroll
    for (int n = 0; n < 4; ++n) {
      const int col = ccol0 + n * 16;
#pragma unroll
      for (int r = 0; r < 4; ++r) {
        const int row = crow0 + m * 16 + r;
        float v = acc[m][n][r];
        if (EPI == 0) {
          ((float*)C0)[(size_t)row * 2560 + col] = v + bias[col];
        } else {
          if (col < 2560)
            ((ushort_t*)C0)[pkaddr(col, row, MROWS)] = f2bf(v + bias[col]);
          else
            ((ushort_t*)C1)[pkaddr(col - 2560, row, MROWS)] = f2bf(v);
        }
      }
    }
}

// ---------------- gate GEMM (packed), fused gx+ga epilogue ----------------
// per head z: C' = xc_head @ gwT_z^T ; gwT packed [z*40+k8][640][8]
__global__ __launch_bounds__(256, 2)
void gate_gemm(const ushort_t* __restrict__ A,      // xcbf packed [320][8192][8]
               const ushort_t* __restrict__ Bw,     // gwT packed
               ushort_t* __restrict__ GX,           // T2 packed
               ushort_t* __restrict__ AAo,          // AA packed
               const float* __restrict__ gxb, const float* __restrict__ gab,
               const float* __restrict__ ctab, const int* __restrict__ seg) {
  constexpr int BM = 128, BN = 64, NF = 2;
  __shared__ char smem[12288];   // A: [4][128][16B]=8KB, B: [4][64][16B]=4KB @8192
  const int tid = threadIdx.x;
  const int w = tid >> 6, lane = tid & 63;
  const int wr = w >> 1, wc = w & 1;
  const int l15 = lane & 15, l4 = lane >> 4;
  const int tm = blockIdx.x * BM;
  const int tn = blockIdx.y * BN;     // 0..576 within head's 640
  const int z = blockIdx.z;

  // staging addresses (contiguous runs)
  const char* aS[2]; int lda_[2];
#pragma unroll
  for (int u = 0; u < 2; ++u) {
    int lb = (u * 256 + tid) * 16;
    int slot = lb >> 11, m = (lb >> 4) & 127;
    aS[u] = (const char*)A + ((size_t)(z * 40 + slot) * MROWS + tm + m) * 16;
    lda_[u] = lb;
  }
  const char* bS; int ldb_;
  {
    int lb = tid * 16;
    int slot = lb >> 10, n = (lb >> 4) & 63;
    bS = (const char*)Bw + ((size_t)(z * 40 + slot) * 640 + tn + n) * 16;
    ldb_ = 8192 + lb;
  }
  const size_t aStep = (size_t)4 * MROWS * 16;
  const size_t bStep = (size_t)4 * 640 * 16;

  f32x4 acc[4][NF] = {};
  const int aRd = l4 * 2048 + (wr * 64 + l15) * 16;
  const int bRd = 8192 + l4 * 1024 + (wc * 32 + l15) * 16;

  for (int kt = 0; kt < 10; ++kt) {
#pragma unroll
    for (int u = 0; u < 2; ++u)
      async_load16(aS[u] + kt * aStep, smem + lda_[u]);
    async_load16(bS + kt * bStep, smem + ldb_);
    __syncthreads();
    short8 af[4], bfr[NF];
#pragma unroll
    for (int mf = 0; mf < 4; ++mf)
      af[mf] = *(const short8*)(smem + aRd + mf * 256);
#pragma unroll
    for (int nf = 0; nf < NF; ++nf)
      bfr[nf] = *(const short8*)(smem + bRd + nf * 256);
#pragma unroll
    for (int mf = 0; mf < 4; ++mf)
#pragma unroll
      for (int nf = 0; nf < NF; ++nf)
        acc[mf][nf] = __builtin_amdgcn_mfma_f32_16x16x32_bf16(af[mf], bfr[nf], acc[mf][nf], 0, 0, 0);
    __syncthreads();
  }

  const int crow0 = tm + wr * 64 + l4 * 4;
  const int ccol0 = tn + wc * 32 + l15;
#pragma unroll
  for (int mf = 0; mf < 4; ++mf) {
#pragma unroll
    for (int nf = 0; nf < NF; ++nf) {
      const int cih = ccol0 + nf * 16;     // 0..639 within head
#pragma unroll
      for (int r = 0; r < 4; ++r) {
        const int row = crow0 + mf * 16 + r;
        if (cih < BW_) {
          const int gc = z * BW_ + cih;
          float v = acc[mf][nf][r] + gxb[gc];
          float xc = bf2f(A[pkaddr(gc, row, MROWS)]);
          GX[pkaddr(gc, row, MROWS)] = f2bf(xc * sigmoidf_(v));
        } else {
          const int gc = z * BW_ + cih - BW_;
          float v = acc[mf][nf][r] + gab[gc];
          float la = ctab[gc] * sigmoidf_(v);
          float av = (seg[row] == 0) ? 0.f : expf(la);
          AAo[pkaddr(gc, row, MROWS)] = f2bf(av);
        }
      }
    }
  }
}

// ---------------- conv (packed): thread = (plane, row), reads 4 packets ----------
__global__ void conv_pk(const ushort_t* __restrict__ xl, const float* __restrict__ convw,
                        const float* __restrict__ convb, ushort_t* __restrict__ xc) {
  int i = blockIdx.x * blockDim.x + threadIdx.x;
  if (i >= 320 * MROWS) return;
  int m = i % MROWS;
  int p = i / MROWS;
  int t = m % LL;
  const ushort_t* pl = xl + (size_t)p * MROWS * 8;
  short8 v0 = {}, v1 = {}, v2 = {}, v3;
  v3 = *(const short8*)(pl + (size_t)m * 8);
  if (t >= 1) v2 = *(const short8*)(pl + (size_t)(m - 1) * 8);
  if (t >= 2) v1 = *(const short8*)(pl + (size_t)(m - 2) * 8);
  if (t >= 3) v0 = *(const short8*)(pl + (size_t)(m - 3) * 8);
  ushort_t o[8];
#pragma unroll
  for (int u = 0; u < 8; ++u) {
    int e = p * 8 + u;
    float4 wv = ((const float4*)convw)[e];
    float acc = convb[e];
    acc += wv.x * bf2f((ushort_t)v0[u]);
    acc += wv.y * bf2f((ushort_t)v1[u]);
    acc += wv.z * bf2f((ushort_t)v2[u]);
    acc += wv.w * bf2f((ushort_t)v3[u]);
    o[u] = f2bf(acc);
  }
  *(short8*)(xc + (size_t)p * MROWS * 8 + (size_t)m * 8) = *(short8*)o;
}

__global__ void conv_state_kernel(const ushort_t* __restrict__ xl, const int* __restrict__ cidx,
                                  float* __restrict__ cs) {
  int i = blockIdx.x * blockDim.x + threadIdx.x;
  if (i >= BB * LRU_ * DCONV_) return;
  int e = (i / DCONV_) % LRU_;
  int b = i / (DCONV_ * LRU_);
  int idx = cidx[i];
  int ts = idx - (DCONV_ - 1);
  float v = 0.f;
  if (ts >= 0 && ts < LL) v = bf2f(xl[pkaddr(e, b * LL + ts, MROWS)]);
  cs[i] = v;
}

// ---------------- chunked scan (packed inputs) ----------------
__global__ void scanA(const ushort_t* __restrict__ AA, const ushort_t* __restrict__ GX,
                      float* __restrict__ cA, float* __restrict__ cH) {
  int i = blockIdx.x * blockDim.x + threadIdx.x;
  if (i >= BB * NCH * LRU_) return;
  int e = i % LRU_;
  int c = (i / LRU_) % NCH;
  int b = i / (LRU_ * NCH);
  float Ap = 1.f, h = 0.f;
  size_t base = pkaddr(e, b * LL + c * CLEN, MROWS);
  for (int t = 0; t < CLEN; ++t) {
    size_t j = base + (size_t)t * 8;
    float a = bf2f(AA[j]);
    float nx = bf2f(GX[j]) * sqrtf(fmaxf(0.f, 1.f - a * a));
    Ap *= a;
    h = a * h + nx;
  }
  cA[i] = Ap; cH[i] = h;
}

__global__ void scanB(const float* __restrict__ cA, const float* __restrict__ cH,
                      float* __restrict__ hInit) {
  int i = blockIdx.x * blockDim.x + threadIdx.x;
  if (i >= BB * LRU_) return;
  int e = i % LRU_;
  int b = i / LRU_;
  float h = 0.f;
  for (int c = 0; c < NCH; ++c) {
    size_t j = ((size_t)b * NCH + c) * LRU_ + e;
    hInit[j] = h;
    h = cA[j] * h + cH[j];
  }
}

__global__ void scanC(const ushort_t* __restrict__ AA, const ushort_t* __restrict__ GXpre,
                      const float* __restrict__ hInit, const ushort_t* __restrict__ ybf,
                      const float* __restrict__ ybias, float* __restrict__ lastH) {
  int i = blockIdx.x * blockDim.x + threadIdx.x;
  if (i >= BB * NCH * LRU_) return;
  int e = i % LRU_;
  int c = (i / LRU_) % NCH;
  int b = i / (LRU_ * NCH);
  float h = hInit[i];
  float yb = ybias[e];
  ushort_t* pre = (ushort_t*)GXpre;
  size_t base = pkaddr(e, b * LL + c * CLEN, MROWS);
  for (int t = 0; t < CLEN; ++t) {
    size_t j = base + (size_t)t * 8;
    float a = bf2f(AA[j]);
    float nx = bf2f(GXpre[j]) * sqrtf(fmaxf(0.f, 1.f - a * a));
    h = a * h + nx;
    float yv = bf2f(ybf[j]) + yb;
    float g = 0.5f * yv * (1.f + erff(yv * 0.70710678118f));
    pre[j] = f2bf(h * g);
  }
  if (c == NCH - 1) lastH[(size_t)b * LRU_ + e] = h;
}

// ---------------- launch ----------------
extern "C" void kernel_launch(void* const* d_in, const int* in_sizes, int n_in,
                              void* d_out, int out_size, void* d_ws, size_t ws_size,
                              hipStream_t stream) {
  const float* x     = (const float*)d_in[0];
  const int*   seg   = (const int*)d_in[1];
  const int*   cidx  = (const int*)d_in[2];
  const float* Wx    = (const float*)d_in[3];
  const float* bx    = (const float*)d_in[4];
  const float* Wy    = (const float*)d_in[5];
  const float* convw = (const float*)d_in[6];
  const float* convb = (const float*)d_in[7];
  const float* gxw   = (const float*)d_in[8];
  const float* gxb   = (const float*)d_in[9];
  const float* gaw   = (const float*)d_in[10];
  const float* gab   = (const float*)d_in[11];
  const float* apar  = (const float*)d_in[12];
  const float* ybias = (const float*)d_in[13];
  const float* Wout  = (const float*)d_in[14];
  const float* bout  = (const float*)d_in[15];

  float* out    = (float*)d_out;
  float* cs_out = out + (size_t)MROWS * WIDTH_;
  float* lh_out = cs_out + (size_t)BB * LRU_ * DCONV_;

  // scratch inside d_out (dead until the final GEMM rewrites the out region)
  ushort_t* ybf = (ushort_t*)d_out;                               // packed, 41.94 MB
  ushort_t* AA  = (ushort_t*)((char*)d_out + (size_t)41943040);   // packed, 41.94 MB

  const size_t SZ_BIG = (size_t)MROWS * LRU_ * 2;       // 41,943,040
  const size_t SZ_WC  = (size_t)(2 * LRU_) * WIDTH_ * 2;// 26,214,400
  const size_t SZ_GW  = (size_t)HEADS_ * 640 * BW_ * 2; // 3,276,800
  const size_t SZ_SM  = (size_t)BB * NCH * LRU_ * 4;    // 1,310,720
  size_t need = SZ_BIG * 3 + SZ_WC + SZ_GW + 10240 + SZ_SM * 3;
  if (ws_size < need) return;

  char* p = (char*)d_ws;
  ushort_t* xpk   = (ushort_t*)p; p += SZ_BIG;  // x packed [320][8192][8]
  ushort_t* wpk   = (ushort_t*)p; p += SZ_WC;   // [Wx;Wy] packed [320][5120][8]; later Wout packed
  ushort_t* T2    = (ushort_t*)p; p += SZ_BIG;  // xl -> GX -> pre (packed)
  ushort_t* xcbf  = (ushort_t*)p; p += SZ_BIG;  // packed
  ushort_t* gwT   = (ushort_t*)p; p += SZ_GW;   // packed [8*40][640][8]
  float*    ctab  = (float*)p;    p += 10240;
  float*    cA    = (float*)p;    p += SZ_SM;
  float*    cH    = (float*)p;    p += SZ_SM;
  float*    hInit = (float*)p;    p += SZ_SM;
  ushort_t* woutpk = wpk;                       // [320][2560][8] after GEMM1

  const int BLK = 256;
  // transpose-pack inputs
  tp_pack<<<dim3(MROWS / 64, WIDTH_ / 64), 256, 0, stream>>>(x, xpk, MROWS, WIDTH_, MROWS, 0);
  tp_pack<<<dim3(LRU_ / 64, WIDTH_ / 64), 256, 0, stream>>>(Wx, wpk, LRU_, WIDTH_, 2 * LRU_, 0);
  tp_pack<<<dim3(LRU_ / 64, WIDTH_ / 64), 256, 0, stream>>>(Wy, wpk, LRU_, WIDTH_, 2 * LRU_, LRU_);

  // fused: [xl | y] = x @ [Wx;Wy]^T   (N=5120, 640 blocks) -> T2, ybf (packed)
  gemm_pk<1><<<640, 512, 0, stream>>>(xpk, wpk, 2 * LRU_, T2, ybf, bx);

  // Wout packed into wpk region (dead after GEMM1; stream-ordered)
  tp_pack<<<dim3(LRU_ / 64, WIDTH_ / 64), 256, 0, stream>>>(Wout, woutpk, WIDTH_, LRU_, WIDTH_, 0);

  conv_pk<<<(320 * MROWS + BLK - 1) / BLK, BLK, 0, stream>>>(T2, convw, convb, xcbf);
  conv_state_kernel<<<(BB * LRU_ * DCONV_ + BLK - 1) / BLK, BLK, 0, stream>>>(T2, cidx, cs_out);

  gw_pack<<<(HEADS_ * BW_ * BW_ + BLK - 1) / BLK, BLK, 0, stream>>>(gxw, gwT, 0, HEADS_ * BW_ * BW_);
  gw_pack<<<(HEADS_ * BW_ * BW_ + BLK - 1) / BLK, BLK, 0, stream>>>(gaw, gwT, BW_, HEADS_ * BW_ * BW_);
  ctab_kernel<<<(LRU_ + BLK - 1) / BLK, BLK, 0, stream>>>(apar, ctab);

  // fused gate GEMM: GX -> T2 (over dead xl), AA -> d_out scratch
  gate_gemm<<<dim3(MROWS / 128, 10, HEADS_), BLK, 0, stream>>>(
      xcbf, gwT, T2, AA, gxb, gab, ctab, seg);

  scanA<<<(BB * NCH * LRU_ + BLK - 1) / BLK, BLK, 0, stream>>>(AA, T2, cA, cH);
  scanB<<<(BB * LRU_ + BLK - 1) / BLK, BLK, 0, stream>>>(cA, cH, hInit);
  scanC<<<(BB * NCH * LRU_ + BLK - 1) / BLK, BLK, 0, stream>>>(AA, T2, hInit, ybf, ybias, lh_out);

  // out = pre @ Wout^T + bout  (N=2560, 320 blocks), f32 row-major
  gemm_pk<0><<<320, 512, 0, stream>>>(T2, woutpk, WIDTH_, out, nullptr, bout);
}

// Round 7
// 572.708 us; speedup vs baseline: 1.7122x; 1.0333x over previous
//
#include <hip/hip_runtime.h>
#include <hip/hip_bf16.h>

#define WIDTH_ 2560
#define LRU_   2560
#define HEADS_ 8
#define BW_    320
#define DCONV_ 4
#define BB     4
#define LL     2048
#define MROWS  (BB*LL)          // 8192
#define NCH    32               // scan chunks
#define CLEN   (LL/NCH)         // 64

typedef unsigned short ushort_t;
typedef __attribute__((ext_vector_type(8))) short short8;
typedef __attribute__((ext_vector_type(4))) float f32x4;

__device__ __forceinline__ unsigned short f2bf(float f) {
  union { float f; unsigned u; } v; v.f = f;
  unsigned r = v.u + 0x7fffu + ((v.u >> 16) & 1u);
  return (unsigned short)(r >> 16);
}
__device__ __forceinline__ float bf2f(unsigned short h) {
  union { unsigned u; float f; } v; v.u = ((unsigned)h) << 16;
  return v.f;
}
__device__ __forceinline__ void async_load16(const void* g, void* l) {
  __builtin_amdgcn_global_load_lds(
      (const __attribute__((address_space(1))) unsigned*)g,
      (__attribute__((address_space(3))) unsigned*)l, 16, 0, 0);
}
__device__ __forceinline__ float sigmoidf_(float x) {
  return 1.f / (1.f + __expf(-x));
}
// packed [C/8][PL][8] address (ushort units)
__device__ __forceinline__ size_t pkaddr(int e, int m, int PL) {
  return ((size_t)(e >> 3) * PL + m) * 8 + (e & 7);
}

// ------------- transpose-pack: f32 [R][C] -> bf16 packed [C/8][PL][8] @ row RO -----
__global__ void tp_pack(const float* __restrict__ src, ushort_t* __restrict__ dst,
                        int R, int C, int PL, int RO) {
  __shared__ float tile[64][65];
  const int r0 = blockIdx.x * 64, c0 = blockIdx.y * 64;
  const int t = threadIdx.x;
#pragma unroll
  for (int it = 0; it < 4; ++it) {
    int row = it * 16 + (t >> 4);
    int col = (t & 15) * 4;
    *(float4*)&tile[row][col] = *(const float4*)&src[(size_t)(r0 + row) * C + c0 + col];
  }
  __syncthreads();
#pragma unroll
  for (int it = 0; it < 2; ++it) {
    int c8 = it * 4 + (t >> 6);     // 0..7
    int m  = t & 63;
    ushort_t o[8];
#pragma unroll
    for (int j = 0; j < 8; ++j) o[j] = f2bf(tile[m][c8 * 8 + j]);
    *(short8*)&dst[((size_t)(c0 / 8 + c8) * PL + RO + r0 + m) * 8] = *(short8*)o;
  }
}

// gate weights: dst[h*40 + k>>3][RO + n][k&7] = w[h][k][n]   (plane rows = 640)
__global__ void gw_pack(const float* __restrict__ w, ushort_t* __restrict__ dst,
                        int RO, int n_) {
  int i = blockIdx.x * blockDim.x + threadIdx.x;
  if (i >= n_) return;
  int n = i % BW_;
  int k = (i / BW_) % BW_;
  int h = i / (BW_ * BW_);
  dst[((size_t)(h * 40 + (k >> 3)) * 640 + RO + n) * 8 + (k & 7)] =
      f2bf(w[((size_t)h * BW_ + k) * BW_ + n]);
}

// ctab[e] = -8 * softplus(a_param[e])
__global__ void ctab_kernel(const float* __restrict__ apar, float* __restrict__ ctab) {
  int e = blockIdx.x * blockDim.x + threadIdx.x;
  if (e >= LRU_) return;
  float ap = apar[e];
  float sp = (ap > 15.f) ? ap : log1pf(expf(ap));
  ctab[e] = -8.f * sp;
}

// ============ 256x256 GEMM, packed operands, m201 8-phase schedule ============
// A packed [320][8192][8]; B packed [320][NPL][8]; K=2560 = 40 K-tiles of 64.
// LDS: A halves (buf*2+h)*16384 in [0,64K); B at 65536+(buf*2+h)*16384.
// Half layout: [slot(8)][m(128)][16B]; staging 2 gloads/thread/half (2KB runs).
// Iter i computes kt=2i (buf0, phases 0-3) and 2i+1 (buf1, phases 4-7).
// Stagger: p0/p1 A(2i+1)->buf1, p2/p3 B(2i+2)->buf0, p4/p5 A(2i+2)->buf0,
//          p6/p7 B(2i+3)->buf1.  vmcnt(4) at p3/p7 only (FIFO: covers next group).

#define STG_A(KT, H, BUF) do { \
  _Pragma("unroll") for (int u_ = 0; u_ < 2; ++u_) \
    async_load16(Ach + aoff[u_] + (size_t)(KT) * aKt + (H) * 2048, \
                 smem + ((BUF) * 2 + (H)) * 16384 + ldst[u_]); } while (0)
#define STG_B(KT, H, BUF) do { \
  _Pragma("unroll") for (int u_ = 0; u_ < 2; ++u_) \
    async_load16(Bch + boff[u_] + (size_t)(KT) * bKt + (H) * 2048, \
                 smem + 65536 + ((BUF) * 2 + (H)) * 16384 + ldst[u_]); } while (0)

#define PHASE(BUF, Q, STAGE_STMT, VMN) do { \
  __builtin_amdgcn_sched_barrier(0); \
  const char* Ah_ = smem + ((BUF) * 2 + wr) * 16384; \
  const char* Bh_ = smem + 65536 + ((BUF) * 2 + (wc >> 1)) * 16384; \
  if ((Q) == 0) { \
    _Pragma("unroll") for (int nf = 0; nf < 4; ++nf) \
      _Pragma("unroll") for (int s = 0; s < 2; ++s) \
        bfr[nf][s] = *(const short8*)(Bh_ + ((s * 4 + l4) * 128 + brow + nf * 16 + l15) * 16); \
  } \
  short8 a_[2][2]; \
  _Pragma("unroll") for (int mm = 0; mm < 2; ++mm) \
    _Pragma("unroll") for (int s = 0; s < 2; ++s) \
      a_[mm][s] = *(const short8*)(Ah_ + ((s * 4 + l4) * 128 + ((Q) * 2 + mm) * 16 + l15) * 16); \
  STAGE_STMT; \
  __builtin_amdgcn_sched_barrier(0); \
  __builtin_amdgcn_s_barrier(); \
  asm volatile("s_waitcnt lgkmcnt(0)" ::: "memory"); \
  __builtin_amdgcn_sched_barrier(0); \
  __builtin_amdgcn_s_setprio(1); \
  _Pragma("unroll") for (int mm = 0; mm < 2; ++mm) \
    _Pragma("unroll") for (int nf = 0; nf < 4; ++nf) \
      _Pragma("unroll") for (int s = 0; s < 2; ++s) \
        acc[(Q) * 2 + mm][nf] = __builtin_amdgcn_mfma_f32_16x16x32_bf16( \
            a_[mm][s], bfr[nf][s], acc[(Q) * 2 + mm][nf], 0, 0, 0); \
  __builtin_amdgcn_s_setprio(0); \
  if ((VMN) == 4)      asm volatile("s_waitcnt vmcnt(4)" ::: "memory"); \
  else if ((VMN) == 0) asm volatile("s_waitcnt vmcnt(0)" ::: "memory"); \
  __builtin_amdgcn_sched_barrier(0); \
  __builtin_amdgcn_s_barrier(); \
} while (0)

// EPI 0: f32 row-major store + bias   EPI 1: split packed bf16 (col<2560->C0+bias, else C1)
template<int EPI>
__global__ __launch_bounds__(512, 2)
void gemm_pk(const ushort_t* __restrict__ A,
             const ushort_t* __restrict__ B, int NPL,
             void* __restrict__ C0, void* __restrict__ C1,
             const float* __restrict__ bias) {
  __shared__ char smem[131072];
  const int tid = threadIdx.x;
  const int lane = tid & 63, w = tid >> 6;
  const int wr = w >> 2, wc = w & 3;
  const int l15 = lane & 15, l4 = lane >> 4;
  const int brow = (wc & 1) * 64;

  // XCD-chunked mapping: XCD x owns tm-band [4x,4x+4), tn fastest (bijective)
  const int nblk = gridDim.x;
  const int TN = nblk >> 5;
  const int x8 = blockIdx.x & 7, c = blockIdx.x >> 3;
  const int tm = (x8 * 4 + c / TN) * 256;
  const int tn = (c % TN) * 256;

  const char* Ach = (const char*)A;
  const char* Bch = (const char*)B;
  const size_t aKt = (size_t)8 * MROWS * 16;
  const size_t bKt = (size_t)8 * NPL * 16;

  // staging offsets: lb=(u*512+tid)*16; slot=lb>>11, m=(lb>>4)&127
  size_t aoff[2], boff[2]; int ldst[2];
#pragma unroll
  for (int u = 0; u < 2; ++u) {
    int lb = (u * 512 + tid) * 16;
    int slot = lb >> 11, m = (lb >> 4) & 127;
    aoff[u] = ((size_t)slot * MROWS + tm + m) * 16;
    boff[u] = ((size_t)slot * NPL + tn + m) * 16;
    ldst[u] = lb;
  }

  f32x4 acc[8][4] = {};
  short8 bfr[4][2];

  // prologue: B(0)h0,h1 A(0)h0,h1 (8 loads) then B(1)h0,h1 (4 loads)
  STG_B(0, 0, 0); STG_B(0, 1, 0); STG_A(0, 0, 0); STG_A(0, 1, 0);
  STG_B(1, 0, 1); STG_B(1, 1, 1);
  asm volatile("s_waitcnt vmcnt(4)" ::: "memory");
  __builtin_amdgcn_sched_barrier(0);
  __builtin_amdgcn_s_barrier();

#pragma unroll 1
  for (int i = 0; i < 20; ++i) {
    const int k1 = 2 * i + 1, k2 = 2 * i + 2, k3 = 2 * i + 3;
    const bool v2 = (k2 < 40), v3 = (k3 < 40);
    PHASE(0, 0, STG_A(k1, 0, 1), -1);
    PHASE(0, 1, STG_A(k1, 1, 1), -1);
    PHASE(0, 2, if (v2) STG_B(k2, 0, 0), -1);
    PHASE(0, 3, if (v2) STG_B(k2, 1, 0), (v2 ? 4 : 0));
    PHASE(1, 0, if (v2) STG_A(k2, 0, 0), -1);
    PHASE(1, 1, if (v2) STG_A(k2, 1, 0), -1);
    PHASE(1, 2, if (v3) STG_B(k3, 0, 1), -1);
    PHASE(1, 3, if (v3) STG_B(k3, 1, 1), (v3 ? 4 : (v2 ? 0 : -1)));
  }

  // epilogue: C row = (lane>>4)*4 + r, col = lane&15
  const int crow0 = tm + wr * 128 + l4 * 4;
  const int ccol0 = tn + wc * 64 + l15;
#pragma unroll
  for (int m = 0; m < 8; ++m)
#pragma unroll
    for (int n = 0; n < 4; ++n) {
      const int col = ccol0 + n * 16;
#pragma unroll
      for (int r = 0; r < 4; ++r) {
        const int row = crow0 + m * 16 + r;
        float v = acc[m][n][r];
        if (EPI == 0) {
          ((float*)C0)[(size_t)row * 2560 + col] = v + bias[col];
        } else {
          if (col < 2560)
            ((ushort_t*)C0)[pkaddr(col, row, MROWS)] = f2bf(v + bias[col]);
          else
            ((ushort_t*)C1)[pkaddr(col - 2560, row, MROWS)] = f2bf(v);
        }
      }
    }
}

// ---------------- gate GEMM (packed), fused gx+ga epilogue ----------------
// per head z: C' = xc_head @ gwT_z^T ; gwT packed [z*40+k8][640][8]
__global__ __launch_bounds__(256, 2)
void gate_gemm(const ushort_t* __restrict__ A,      // xcbf packed [320][8192][8]
               const ushort_t* __restrict__ Bw,     // gwT packed
               ushort_t* __restrict__ GX,           // T2 packed
               ushort_t* __restrict__ AAo,          // AA packed
               const float* __restrict__ gxb, const float* __restrict__ gab,
               const float* __restrict__ ctab, const int* __restrict__ seg) {
  constexpr int BM = 128, NF = 2;
  __shared__ char smem[12288];   // A: [4][128][16B]=8KB, B: [4][64][16B]=4KB @8192
  const int tid = threadIdx.x;
  const int w = tid >> 6, lane = tid & 63;
  const int wr = w >> 1, wc = w & 1;
  const int l15 = lane & 15, l4 = lane >> 4;
  const int tm = blockIdx.x * BM;
  const int tn = blockIdx.y * 64;     // 0..576 within head's 640
  const int z = blockIdx.z;

  // staging addresses (contiguous runs)
  const char* aS[2]; int lda_[2];
#pragma unroll
  for (int u = 0; u < 2; ++u) {
    int lb = (u * 256 + tid) * 16;
    int slot = lb >> 11, m = (lb >> 4) & 127;
    aS[u] = (const char*)A + ((size_t)(z * 40 + slot) * MROWS + tm + m) * 16;
    lda_[u] = lb;
  }
  const char* bS; int ldb_;
  {
    int lb = tid * 16;
    int slot = lb >> 10, n = (lb >> 4) & 63;
    bS = (const char*)Bw + ((size_t)(z * 40 + slot) * 640 + tn + n) * 16;
    ldb_ = 8192 + lb;
  }
  const size_t aStep = (size_t)4 * MROWS * 16;
  const size_t bStep = (size_t)4 * 640 * 16;

  f32x4 acc[4][NF] = {};
  const int aRd = l4 * 2048 + (wr * 64 + l15) * 16;
  const int bRd = 8192 + l4 * 1024 + (wc * 32 + l15) * 16;

  for (int kt = 0; kt < 10; ++kt) {
#pragma unroll
    for (int u = 0; u < 2; ++u)
      async_load16(aS[u] + kt * aStep, smem + lda_[u]);
    async_load16(bS + kt * bStep, smem + ldb_);
    __syncthreads();
    short8 af[4], bfr[NF];
#pragma unroll
    for (int mf = 0; mf < 4; ++mf)
      af[mf] = *(const short8*)(smem + aRd + mf * 256);
#pragma unroll
    for (int nf = 0; nf < NF; ++nf)
      bfr[nf] = *(const short8*)(smem + bRd + nf * 256);
#pragma unroll
    for (int mf = 0; mf < 4; ++mf)
#pragma unroll
      for (int nf = 0; nf < NF; ++nf)
        acc[mf][nf] = __builtin_amdgcn_mfma_f32_16x16x32_bf16(af[mf], bfr[nf], acc[mf][nf], 0, 0, 0);
    __syncthreads();
  }

  const int crow0 = tm + wr * 64 + l4 * 4;
  const int ccol0 = tn + wc * 32 + l15;
#pragma unroll
  for (int mf = 0; mf < 4; ++mf) {
#pragma unroll
    for (int nf = 0; nf < NF; ++nf) {
      const int cih = ccol0 + nf * 16;     // 0..639 within head
#pragma unroll
      for (int r = 0; r < 4; ++r) {
        const int row = crow0 + mf * 16 + r;
        if (cih < BW_) {
          const int gc = z * BW_ + cih;
          float v = acc[mf][nf][r] + gxb[gc];
          float xc = bf2f(A[pkaddr(gc, row, MROWS)]);
          GX[pkaddr(gc, row, MROWS)] = f2bf(xc * sigmoidf_(v));
        } else {
          const int gc = z * BW_ + cih - BW_;
          float v = acc[mf][nf][r] + gab[gc];
          float la = ctab[gc] * sigmoidf_(v);
          float av = (seg[row] == 0) ? 0.f : expf(la);
          AAo[pkaddr(gc, row, MROWS)] = f2bf(av);
        }
      }
    }
  }
}

// ---------------- conv (packed): thread = (plane, row), reads 4 packets ----------
__global__ void conv_pk(const ushort_t* __restrict__ xl, const float* __restrict__ convw,
                        const float* __restrict__ convb, ushort_t* __restrict__ xc) {
  int i = blockIdx.x * blockDim.x + threadIdx.x;
  if (i >= 320 * MROWS) return;
  int m = i % MROWS;
  int p = i / MROWS;
  int t = m % LL;
  const ushort_t* pl = xl + (size_t)p * MROWS * 8;
  short8 v0 = {}, v1 = {}, v2 = {}, v3;
  v3 = *(const short8*)(pl + (size_t)m * 8);
  if (t >= 1) v2 = *(const short8*)(pl + (size_t)(m - 1) * 8);
  if (t >= 2) v1 = *(const short8*)(pl + (size_t)(m - 2) * 8);
  if (t >= 3) v0 = *(const short8*)(pl + (size_t)(m - 3) * 8);
  ushort_t o[8];
#pragma unroll
  for (int u = 0; u < 8; ++u) {
    int e = p * 8 + u;
    float4 wv = ((const float4*)convw)[e];
    float acc = convb[e];
    acc += wv.x * bf2f((ushort_t)v0[u]);
    acc += wv.y * bf2f((ushort_t)v1[u]);
    acc += wv.z * bf2f((ushort_t)v2[u]);
    acc += wv.w * bf2f((ushort_t)v3[u]);
    o[u] = f2bf(acc);
  }
  *(short8*)(xc + (size_t)p * MROWS * 8 + (size_t)m * 8) = *(short8*)o;
}

__global__ void conv_state_kernel(const ushort_t* __restrict__ xl, const int* __restrict__ cidx,
                                  float* __restrict__ cs) {
  int i = blockIdx.x * blockDim.x + threadIdx.x;
  if (i >= BB * LRU_ * DCONV_) return;
  int e = (i / DCONV_) % LRU_;
  int b = i / (DCONV_ * LRU_);
  int idx = cidx[i];
  int ts = idx - (DCONV_ - 1);
  float v = 0.f;
  if (ts >= 0 && ts < LL) v = bf2f(xl[pkaddr(e, b * LL + ts, MROWS)]);
  cs[i] = v;
}

// ---------------- chunked scan (packed inputs) ----------------
__global__ void scanA(const ushort_t* __restrict__ AA, const ushort_t* __restrict__ GX,
                      float* __restrict__ cA, float* __restrict__ cH) {
  int i = blockIdx.x * blockDim.x + threadIdx.x;
  if (i >= BB * NCH * LRU_) return;
  int e = i % LRU_;
  int c = (i / LRU_) % NCH;
  int b = i / (LRU_ * NCH);
  float Ap = 1.f, h = 0.f;
  size_t base = pkaddr(e, b * LL + c * CLEN, MROWS);
  for (int t = 0; t < CLEN; ++t) {
    size_t j = base + (size_t)t * 8;
    float a = bf2f(AA[j]);
    float nx = bf2f(GX[j]) * sqrtf(fmaxf(0.f, 1.f - a * a));
    Ap *= a;
    h = a * h + nx;
  }
  cA[i] = Ap; cH[i] = h;
}

__global__ void scanB(const float* __restrict__ cA, const float* __restrict__ cH,
                      float* __restrict__ hInit) {
  int i = blockIdx.x * blockDim.x + threadIdx.x;
  if (i >= BB * LRU_) return;
  int e = i % LRU_;
  int b = i / LRU_;
  float h = 0.f;
  for (int c = 0; c < NCH; ++c) {
    size_t j = ((size_t)b * NCH + c) * LRU_ + e;
    hInit[j] = h;
    h = cA[j] * h + cH[j];
  }
}

__global__ void scanC(const ushort_t* __restrict__ AA, const ushort_t* __restrict__ GXpre,
                      const float* __restrict__ hInit, const ushort_t* __restrict__ ybf,
                      const float* __restrict__ ybias, float* __restrict__ lastH) {
  int i = blockIdx.x * blockDim.x + threadIdx.x;
  if (i >= BB * NCH * LRU_) return;
  int e = i % LRU_;
  int c = (i / LRU_) % NCH;
  int b = i / (LRU_ * NCH);
  float h = hInit[i];
  float yb = ybias[e];
  ushort_t* pre = (ushort_t*)GXpre;
  size_t base = pkaddr(e, b * LL + c * CLEN, MROWS);
  for (int t = 0; t < CLEN; ++t) {
    size_t j = base + (size_t)t * 8;
    float a = bf2f(AA[j]);
    float nx = bf2f(GXpre[j]) * sqrtf(fmaxf(0.f, 1.f - a * a));
    h = a * h + nx;
    float yv = bf2f(ybf[j]) + yb;
    float g = 0.5f * yv * (1.f + erff(yv * 0.70710678118f));
    pre[j] = f2bf(h * g);
  }
  if (c == NCH - 1) lastH[(size_t)b * LRU_ + e] = h;
}

// ---------------- launch ----------------
extern "C" void kernel_launch(void* const* d_in, const int* in_sizes, int n_in,
                              void* d_out, int out_size, void* d_ws, size_t ws_size,
                              hipStream_t stream) {
  const float* x     = (const float*)d_in[0];
  const int*   seg   = (const int*)d_in[1];
  const int*   cidx  = (const int*)d_in[2];
  const float* Wx    = (const float*)d_in[3];
  const float* bx    = (const float*)d_in[4];
  const float* Wy    = (const float*)d_in[5];
  const float* convw = (const float*)d_in[6];
  const float* convb = (const float*)d_in[7];
  const float* gxw   = (const float*)d_in[8];
  const float* gxb   = (const float*)d_in[9];
  const float* gaw   = (const float*)d_in[10];
  const float* gab   = (const float*)d_in[11];
  const float* apar  = (const float*)d_in[12];
  const float* ybias = (const float*)d_in[13];
  const float* Wout  = (const float*)d_in[14];
  const float* bout  = (const float*)d_in[15];

  float* out    = (float*)d_out;
  float* cs_out = out + (size_t)MROWS * WIDTH_;
  float* lh_out = cs_out + (size_t)BB * LRU_ * DCONV_;

  // scratch inside d_out (dead until the final GEMM rewrites the out region)
  ushort_t* ybf = (ushort_t*)d_out;                               // packed, 41.94 MB
  ushort_t* AA  = (ushort_t*)((char*)d_out + (size_t)41943040);   // packed, 41.94 MB

  const size_t SZ_BIG = (size_t)MROWS * LRU_ * 2;       // 41,943,040
  const size_t SZ_WC  = (size_t)(2 * LRU_) * WIDTH_ * 2;// 26,214,400
  const size_t SZ_GW  = (size_t)HEADS_ * 640 * BW_ * 2; // 3,276,800
  const size_t SZ_SM  = (size_t)BB * NCH * LRU_ * 4;    // 1,310,720
  size_t need = SZ_BIG * 3 + SZ_WC + SZ_GW + 10240 + SZ_SM * 3;
  if (ws_size < need) return;

  char* p = (char*)d_ws;
  ushort_t* xpk   = (ushort_t*)p; p += SZ_BIG;  // x packed [320][8192][8]
  ushort_t* wpk   = (ushort_t*)p; p += SZ_WC;   // [Wx;Wy] packed [320][5120][8]; later Wout packed
  ushort_t* T2    = (ushort_t*)p; p += SZ_BIG;  // xl -> GX -> pre (packed)
  ushort_t* xcbf  = (ushort_t*)p; p += SZ_BIG;  // packed
  ushort_t* gwT   = (ushort_t*)p; p += SZ_GW;   // packed [8*40][640][8]
  float*    ctab  = (float*)p;    p += 10240;
  float*    cA    = (float*)p;    p += SZ_SM;
  float*    cH    = (float*)p;    p += SZ_SM;
  float*    hInit = (float*)p;    p += SZ_SM;
  ushort_t* woutpk = wpk;                       // [320][2560][8] after GEMM1

  const int BLK = 256;
  // transpose-pack inputs
  tp_pack<<<dim3(MROWS / 64, WIDTH_ / 64), 256, 0, stream>>>(x, xpk, MROWS, WIDTH_, MROWS, 0);
  tp_pack<<<dim3(LRU_ / 64, WIDTH_ / 64), 256, 0, stream>>>(Wx, wpk, LRU_, WIDTH_, 2 * LRU_, 0);
  tp_pack<<<dim3(LRU_ / 64, WIDTH_ / 64), 256, 0, stream>>>(Wy, wpk, LRU_, WIDTH_, 2 * LRU_, LRU_);

  // fused: [xl | y] = x @ [Wx;Wy]^T   (N=5120, 640 blocks) -> T2, ybf (packed)
  gemm_pk<1><<<640, 512, 0, stream>>>(xpk, wpk, 2 * LRU_, T2, ybf, bx);

  // Wout packed into wpk region (dead after GEMM1; stream-ordered)
  tp_pack<<<dim3(LRU_ / 64, WIDTH_ / 64), 256, 0, stream>>>(Wout, woutpk, WIDTH_, LRU_, WIDTH_, 0);

  conv_pk<<<(320 * MROWS + BLK - 1) / BLK, BLK, 0, stream>>>(T2, convw, convb, xcbf);
  conv_state_kernel<<<(BB * LRU_ * DCONV_ + BLK - 1) / BLK, BLK, 0, stream>>>(T2, cidx, cs_out);

  gw_pack<<<(HEADS_ * BW_ * BW_ + BLK - 1) / BLK, BLK, 0, stream>>>(gxw, gwT, 0, HEADS_ * BW_ * BW_);
  gw_pack<<<(HEADS_ * BW_ * BW_ + BLK - 1) / BLK, BLK, 0, stream>>>(gaw, gwT, BW_, HEADS_ * BW_ * BW_);
  ctab_kernel<<<(LRU_ + BLK - 1) / BLK, BLK, 0, stream>>>(apar, ctab);

  // fused gate GEMM: GX -> T2 (over dead xl), AA -> d_out scratch
  gate_gemm<<<dim3(MROWS / 128, 10, HEADS_), BLK, 0, stream>>>(
      xcbf, gwT, T2, AA, gxb, gab, ctab, seg);

  scanA<<<(BB * NCH * LRU_ + BLK - 1) / BLK, BLK, 0, stream>>>(AA, T2, cA, cH);
  scanB<<<(BB * LRU_ + BLK - 1) / BLK, BLK, 0, stream>>>(cA, cH, hInit);
  scanC<<<(BB * NCH * LRU_ + BLK - 1) / BLK, BLK, 0, stream>>>(AA, T2, hInit, ybf, ybias, lh_out);

  // out = pre @ Wout^T + bout  (N=2560, 320 blocks), f32 row-major
  gemm_pk<0><<<320, 512, 0, stream>>>(T2, woutpk, WIDTH_, out, nullptr, bout);
}